// Round 1
// baseline (640.622 us; speedup 1.0000x reference)
//
#include <hip/hip_runtime.h>
#include <math.h>

#define BB 8
#define HH 352
#define WW 352
#define IMG (HH * WW)          // 123904
#define NPIX (BB * IMG)        // 991232
#define THREADS 256
#define NBLK (NPIX / THREADS)  // 3872 exactly

__device__ __forceinline__ float sigmoidf(float x) {
    return 1.0f / (1.0f + expf(-x));
}

// block-wide sum of v, one double atomicAdd per block
__device__ __forceinline__ void block_reduce_add(float v, double* acc) {
    #pragma unroll
    for (int off = 32; off > 0; off >>= 1)
        v += __shfl_down(v, off, 64);
    __shared__ float smem[4];
    int lane = threadIdx.x & 63;
    int wid  = threadIdx.x >> 6;
    if (lane == 0) smem[wid] = v;
    __syncthreads();
    if (threadIdx.x == 0) {
        float s = smem[0] + smem[1] + smem[2] + smem[3];
        atomicAdd(acc, (double)s);
    }
}

// edge_map[b,h,w] = (0 < sum_k con[b,k,h,w] < 8); also count positives
__global__ void k_edgemap(const int* __restrict__ con,
                          float* __restrict__ emap,
                          unsigned int* __restrict__ npos) {
    int idx = blockIdx.x * THREADS + threadIdx.x;   // pixel index over NPIX
    int b = idx / IMG;
    int r = idx - b * IMG;
    const int* base = con + (size_t)b * 8 * IMG + r;
    int s = 0;
    #pragma unroll
    for (int k = 0; k < 8; k++) s += base[(size_t)k * IMG];
    float em = (s > 0 && s < 8) ? 1.0f : 0.0f;
    emap[idx] = em;
    unsigned long long m = __ballot(em != 0.0f);
    if ((threadIdx.x & 63) == 0)
        atomicAdd(npos, (unsigned int)__popcll(m));
}

// edge_l = sum_i bce2d_new(up_edge[i], edge_map)
__global__ void k_edgeloss(const float* __restrict__ up_edge,
                           const float* __restrict__ emap,
                           const unsigned int* __restrict__ npos,
                           double* __restrict__ acc) {
    int idx = blockIdx.x * THREADS + threadIdx.x;
    float np_  = (float)(*npos);
    float tot  = (float)NPIX;
    float nn   = tot - np_;
    float wpos = nn / tot;
    float wneg = 1.1f * np_ / tot;
    float t  = emap[idx];
    float wt = (t != 0.0f) ? wpos : wneg;
    float local = 0.0f;
    #pragma unroll
    for (int i = 0; i < 3; i++) {
        float x  = up_edge[(size_t)i * NPIX + idx];
        float ce = fmaxf(x, 0.0f) - x * t + log1pf(expf(-fabsf(x)));
        local += wt * ce;
    }
    block_reduce_add(local, acc);
}

// sal_l over all 4 logit tensors, fused: per pixel reads con once.
__global__ void k_sal(const float* __restrict__ up_sal,
                      const float* __restrict__ up_sal_f,
                      const float* __restrict__ target,
                      const int* __restrict__ con,
                      const float* __restrict__ emap,
                      double* __restrict__ acc) {
    int idx = blockIdx.x * THREADS + threadIdx.x;
    int b = idx / IMG;
    int r = idx - b * IMG;
    int h = r / WW;
    int w = r - h * WW;

    float em  = emap[idx];
    float tgt = target[idx];

    const int* cbase = con + (size_t)b * 8 * IMG + r;
    float cf[8];
    #pragma unroll
    for (int k = 0; k < 8; k++) cf[k] = (float)cbase[(size_t)k * IMG];

    // vote[k] = sigmoid(c_k(h,w)) * sigmoid(c_{7-k}(h+dr,w+dc)), zero-filled OOB
    const int drs[8] = {-1, -1, -1,  0, 0,  1, 1, 1};
    const int dcs[8] = {-1,  0,  1, -1, 1, -1, 0, 1};

    float local = 0.0f;
    #pragma unroll
    for (int s = 0; s < 4; s++) {
        const float* tb = (s < 2) ? (up_sal + (size_t)s * 8 * NPIX)
                                  : (up_sal_f + (size_t)(s - 2) * 8 * NPIX);
        const float* base = tb + (size_t)b * 8 * IMG;

        float pc[8];
        #pragma unroll
        for (int c = 0; c < 8; c++)
            pc[c] = sigmoidf(base[(size_t)c * IMG + r]);

        float vsum = 0.0f, vmin = 1e30f;
        float vb = 0.0f, pb = 0.0f;
        #pragma unroll
        for (int k = 0; k < 8; k++) {
            int hn = h + drs[k], wn = w + dcs[k];
            float pn = 0.0f;
            if (hn >= 0 && hn < HH && wn >= 0 && wn < WW)
                pn = sigmoidf(base[(size_t)(7 - k) * IMG + hn * WW + wn]);
            float v = pc[k] * pn;
            vsum += v;
            vmin = fminf(vmin, v);
            float t = cf[k];
            // t is exactly 0 or 1 -> BCE collapses to one clamped log term
            float lv = (t != 0.0f) ? fmaxf(logf(v), -100.0f)
                                   : fmaxf(log1pf(-v), -100.0f);
            vb -= lv;
            float lp = (t != 0.0f) ? fmaxf(logf(pc[k]), -100.0f)
                                   : fmaxf(log1pf(-pc[k]), -100.0f);
            pb -= lp;
        }
        float glo = vsum * 0.125f;
        float dec = glo * (1.0f - em) + (1.0f - vmin) * em;
        float logp   = fmaxf(logf(dec), -100.0f);
        float log1mp = fmaxf(log1pf(-dec), -100.0f);
        local += -(tgt * logp + (1.0f - tgt) * log1mp);   // dl term
        local += 0.2f * vb + 0.8f * pb;
    }
    block_reduce_add(local, acc);
}

__global__ void k_final(const double* __restrict__ acc, float* __restrict__ out) {
    if (threadIdx.x == 0) {
        double e = acc[0], s = acc[1], l = e + s;
        out[0] = (float)l;
        out[1] = (float)e;
        out[2] = (float)s;
        out[3] = (float)l;
    }
}

extern "C" void kernel_launch(void* const* d_in, const int* in_sizes, int n_in,
                              void* d_out, int out_size, void* d_ws, size_t ws_size,
                              hipStream_t stream) {
    const float* up_edge  = (const float*)d_in[0];  // [3,B,1,H,W]
    const float* up_sal   = (const float*)d_in[1];  // [2,B,8,H,W]
    const float* up_sal_f = (const float*)d_in[2];  // [2,B,8,H,W]
    const float* target   = (const float*)d_in[3];  // [B,1,H,W]
    const int*   con      = (const int*)d_in[4];    // [B,8,H,W]
    float* out = (float*)d_out;

    // ws layout: [0..15] double acc[2] (edge_l, sal_l); [16..19] uint num_pos;
    //            [64 ...] float edge_map[NPIX]
    double*       acc  = (double*)d_ws;
    unsigned int* npos = (unsigned int*)((char*)d_ws + 16);
    float*        emap = (float*)((char*)d_ws + 64);

    hipMemsetAsync(d_ws, 0, 64, stream);
    k_edgemap<<<NBLK, THREADS, 0, stream>>>(con, emap, npos);
    k_edgeloss<<<NBLK, THREADS, 0, stream>>>(up_edge, emap, npos, acc + 0);
    k_sal<<<NBLK, THREADS, 0, stream>>>(up_sal, up_sal_f, target, con, emap, acc + 1);
    k_final<<<1, 64, 0, stream>>>(acc, out);
}

// Round 4
// 470.013 us; speedup vs baseline: 1.3630x; 1.3630x over previous
//
#include <hip/hip_runtime.h>
#include <math.h>

#define BB 8
#define HH 352
#define WW 352
#define IMG (HH * WW)          // 123904
#define NPIX (BB * IMG)        // 991232
#define THREADS 256
#define NBLK (NPIX / THREADS)  // 3872 exactly

__device__ __forceinline__ float rcpf_(float x) { return __builtin_amdgcn_rcpf(x); }

__device__ __forceinline__ float wave_reduce(float v) {
    #pragma unroll
    for (int off = 32; off > 0; off >>= 1)
        v += __shfl_down(v, off, 64);
    return v;
}

// Edge loss, weight-factored: accumulates S_pos = sum_{em=1} ce, S_neg = sum_{em=0} ce,
// and npos. Weights applied in k_final. edge_map recomputed from con (no pre-pass).
__global__ void k_edge(const float* __restrict__ up_edge,
                       const int* __restrict__ con,
                       double* __restrict__ acc,           // acc[0]=S_pos, acc[1]=S_neg
                       unsigned int* __restrict__ npos) {
    int idx = blockIdx.x * THREADS + threadIdx.x;
    int b = idx / IMG;
    int r = idx - b * IMG;
    const int* cb = con + (size_t)b * 8 * IMG + r;
    int s = 0;
    #pragma unroll
    for (int k = 0; k < 8; k++) s += cb[(size_t)k * IMG];
    float em = (s > 0 && s < 8) ? 1.0f : 0.0f;

    float ce = 0.0f;
    #pragma unroll
    for (int i = 0; i < 3; i++) {
        float x = up_edge[(size_t)i * NPIX + idx];
        ce += fmaxf(x, 0.0f) - x * em + __logf(1.0f + __expf(-fabsf(x)));
    }
    float sp = (em != 0.0f) ? ce : 0.0f;
    float sn = (em != 0.0f) ? 0.0f : ce;

    sp = wave_reduce(sp);
    sn = wave_reduce(sn);
    unsigned long long m = __ballot(em != 0.0f);

    __shared__ float smp[4], smn[4];
    __shared__ unsigned int smc[4];
    int lane = threadIdx.x & 63, wid = threadIdx.x >> 6;
    if (lane == 0) { smp[wid] = sp; smn[wid] = sn; smc[wid] = (unsigned)__popcll(m); }
    __syncthreads();
    if (threadIdx.x == 0) {
        atomicAdd(acc + 0, (double)(smp[0] + smp[1] + smp[2] + smp[3]));
        atomicAdd(acc + 1, (double)(smn[0] + smn[1] + smn[2] + smn[3]));
        atomicAdd(npos, smc[0] + smc[1] + smc[2] + smc[3]);
    }
}

// Sal loss: one thread per (pixel, tensor). Branch-free, fast-math, loads hoisted.
__global__ void k_sal(const float* __restrict__ up_sal,
                      const float* __restrict__ up_sal_f,
                      const float* __restrict__ target,
                      const int* __restrict__ con,
                      double* __restrict__ acc) {
    int idx = blockIdx.x * THREADS + threadIdx.x;   // pixel
    int s4  = blockIdx.y;                           // which logit tensor (0..3)
    int b = idx / IMG;
    int r = idx - b * IMG;
    int h = r / WW;
    int w = r - h * WW;

    const int* cb = con + (size_t)b * 8 * IMG + r;
    int cs = 0;
    float cf[8];
    #pragma unroll
    for (int k = 0; k < 8; k++) {
        int c = cb[(size_t)k * IMG];
        cs += c;
        cf[k] = (float)c;
    }
    float em  = (cs > 0 && cs < 8) ? 1.0f : 0.0f;
    float tgt = target[idx];

    const float* tb = (s4 < 2) ? (up_sal + (size_t)s4 * 8 * NPIX)
                               : (up_sal_f + (size_t)(s4 - 2) * 8 * NPIX);
    const float* base = tb + (size_t)b * 8 * IMG;

    const int drs[8] = {-1, -1, -1,  0, 0,  1, 1, 1};
    const int dcs[8] = {-1,  0,  1, -1, 1, -1, 0, 1};

    // load all logits up-front, branch-free (clamped addresses, OOB via select)
    float xc[8], xn[8], okf[8];
    #pragma unroll
    for (int k = 0; k < 8; k++) {
        xc[k] = base[(size_t)k * IMG + r];
        int hn = h + drs[k], wn = w + dcs[k];
        bool ok = ((unsigned)hn < (unsigned)HH) && ((unsigned)wn < (unsigned)WW);
        int hc = min(max(hn, 0), HH - 1);
        int wc = min(max(wn, 0), WW - 1);
        xn[k]  = base[(size_t)(7 - k) * IMG + hc * WW + wc];
        okf[k] = ok ? 1.0f : 0.0f;
    }

    float vsum = 0.0f, vmin = 1e30f, vb = 0.0f, pb = 0.0f;
    #pragma unroll
    for (int k = 0; k < 8; k++) {
        float e  = __expf(-xc[k]);
        float pc = rcpf_(1.0f + e);          // sigmoid(xc)
        float sc = __logf(1.0f + e);         // -log pc  (softplus(-xc))
        float en = __expf(-xn[k]);
        float pn = rcpf_(1.0f + en) * okf[k];
        float sn = (okf[k] != 0.0f) ? __logf(1.0f + en) : 1e30f;

        float v = pc * pn;
        vsum += v;
        vmin = fminf(vmin, v);

        float t    = cf[k];
        float l1mv = __logf(1.0f - v);       // log(1-v) <= 0
        float vbk  = (t != 0.0f) ? (sc + sn) : (-l1mv);
        vb += fminf(vbk, 100.0f);
        float pbk  = (t != 0.0f) ? sc : (xc[k] + sc);  // -log p  /  -log(1-p)
        pb += fminf(pbk, 100.0f);
    }

    float glo = vsum * 0.125f;
    float dec = (em != 0.0f) ? (1.0f - vmin) : glo;
    float lgd  = fmaxf(__logf(dec), -100.0f);
    float lg1d = fmaxf(__logf(1.0f - dec), -100.0f);
    float local = -(tgt * lgd + (1.0f - tgt) * lg1d) + 0.2f * vb + 0.8f * pb;

    local = wave_reduce(local);
    __shared__ float sm[4];
    int lane = threadIdx.x & 63, wid = threadIdx.x >> 6;
    if (lane == 0) sm[wid] = local;
    __syncthreads();
    if (threadIdx.x == 0)
        atomicAdd(acc, (double)(sm[0] + sm[1] + sm[2] + sm[3]));
}

__global__ void k_final(const double* __restrict__ acc,
                        const unsigned int* __restrict__ npos,
                        float* __restrict__ out) {
    if (threadIdx.x == 0) {
        double np_  = (double)(*npos);
        double tot  = (double)NPIX;
        double nn   = tot - np_;
        double wpos = nn / tot;
        double wneg = 1.1 * np_ / tot;
        double e  = wpos * acc[0] + wneg * acc[1];
        double sl = acc[2];
        double l  = e + sl;
        out[0] = (float)l;
        out[1] = (float)e;
        out[2] = (float)sl;
        out[3] = (float)l;
    }
}

extern "C" void kernel_launch(void* const* d_in, const int* in_sizes, int n_in,
                              void* d_out, int out_size, void* d_ws, size_t ws_size,
                              hipStream_t stream) {
    const float* up_edge  = (const float*)d_in[0];  // [3,B,1,H,W]
    const float* up_sal   = (const float*)d_in[1];  // [2,B,8,H,W]
    const float* up_sal_f = (const float*)d_in[2];  // [2,B,8,H,W]
    const float* target   = (const float*)d_in[3];  // [B,1,H,W]
    const int*   con      = (const int*)d_in[4];    // [B,8,H,W]
    float* out = (float*)d_out;

    // ws: acc[0]=S_pos, acc[1]=S_neg, acc[2]=sal_l (doubles); npos uint at +24
    double*       acc  = (double*)d_ws;
    unsigned int* npos = (unsigned int*)((char*)d_ws + 24);

    hipMemsetAsync(d_ws, 0, 64, stream);
    k_edge<<<NBLK, THREADS, 0, stream>>>(up_edge, con, acc, npos);
    k_sal<<<dim3(NBLK, 4), THREADS, 0, stream>>>(up_sal, up_sal_f, target, con, acc + 2);
    k_final<<<1, 64, 0, stream>>>(acc, npos, out);
}

// Round 5
// 239.783 us; speedup vs baseline: 2.6717x; 1.9602x over previous
//
#include <hip/hip_runtime.h>
#include <math.h>

#define HH 352
#define WW 352
#define IMG (HH * WW)          // 123904
#define NPIX (8 * IMG)         // 991232 (B=8)
#define NG (NPIX / 4)          // 247808 pixel-groups (float4 blocks)
#define IMG4 (IMG / 4)         // 30976 groups per image
#define WB (WW / 4)            // 88 blocks per row
#define THREADS 256
#define GBLK (NG / THREADS)    // 968 exactly

typedef float f4 __attribute__((ext_vector_type(4)));
typedef int   i4 __attribute__((ext_vector_type(4)));

__device__ __forceinline__ float rcpf_(float x) { return __builtin_amdgcn_rcpf(x); }

// dword-aligned (possibly 16B-unaligned) float4 load
__device__ __forceinline__ f4 loadu4(const float* p) {
    f4 v;
    __builtin_memcpy(&v, p, 16);
    return v;
}

__device__ __forceinline__ float wave_reduce_f(float v) {
    #pragma unroll
    for (int off = 32; off > 0; off >>= 1) v += __shfl_down(v, off, 64);
    return v;
}
__device__ __forceinline__ int wave_reduce_i(int v) {
    #pragma unroll
    for (int off = 32; off > 0; off >>= 1) v += __shfl_down(v, off, 64);
    return v;
}

// Edge loss (weight-factored) + pack con into 1 byte/pixel for k_sal.
__global__ void k_edge(const float* __restrict__ up_edge,
                       const int* __restrict__ con,
                       unsigned int* __restrict__ packed,
                       double* __restrict__ acc,            // acc[0]=S_pos, acc[1]=S_neg
                       unsigned int* __restrict__ npos) {
    int g = blockIdx.x * THREADS + threadIdx.x;   // pixel-group
    int b = g / IMG4;
    int r4 = g - b * IMG4;
    const int* cb = con + (size_t)b * 8 * IMG + 4 * (size_t)r4;

    i4 c[8];
    #pragma unroll
    for (int k = 0; k < 8; k++) c[k] = *(const i4*)(cb + (size_t)k * IMG);
    f4 x[3];
    #pragma unroll
    for (int i = 0; i < 3; i++)
        x[i] = *(const f4*)(up_edge + (size_t)i * NPIX + 4 * (size_t)g);

    unsigned int pk = 0;
    float sp = 0.0f, sn = 0.0f;
    int cnt = 0;
    #pragma unroll
    for (int j = 0; j < 4; j++) {
        int s = 0;
        unsigned int byte = 0;
        #pragma unroll
        for (int k = 0; k < 8; k++) {
            int cv = c[k][j];
            s += cv;
            byte |= ((unsigned int)cv) << k;
        }
        pk |= byte << (8 * j);
        float em = (s > 0 && s < 8) ? 1.0f : 0.0f;
        float cej = 0.0f;
        #pragma unroll
        for (int i = 0; i < 3; i++) {
            float xx = x[i][j];
            cej += fmaxf(xx, 0.0f) - xx * em + __logf(1.0f + __expf(-fabsf(xx)));
        }
        sp += em * cej;
        sn += (1.0f - em) * cej;
        cnt += (int)em;
    }
    packed[g] = pk;

    sp = wave_reduce_f(sp);
    sn = wave_reduce_f(sn);
    cnt = wave_reduce_i(cnt);

    __shared__ float smp[4], smn[4];
    __shared__ int smc[4];
    int lane = threadIdx.x & 63, wid = threadIdx.x >> 6;
    if (lane == 0) { smp[wid] = sp; smn[wid] = sn; smc[wid] = cnt; }
    __syncthreads();
    if (threadIdx.x == 0) {
        atomicAdd(acc + 0, (double)(smp[0] + smp[1] + smp[2] + smp[3]));
        atomicAdd(acc + 1, (double)(smn[0] + smn[1] + smn[2] + smn[3]));
        atomicAdd(npos, (unsigned int)(smc[0] + smc[1] + smc[2] + smc[3]));
    }
}

// Sal loss: one thread per (4-pixel group, tensor). All loads wide & independent.
__global__ void k_sal(const float* __restrict__ up_sal,
                      const float* __restrict__ up_sal_f,
                      const float* __restrict__ target,
                      const unsigned int* __restrict__ packed,
                      double* __restrict__ acc) {
    int g  = blockIdx.x * THREADS + threadIdx.x;  // pixel-group
    int s4 = blockIdx.y;                          // tensor 0..3
    int b  = g / IMG4;
    int r4 = g - b * IMG4;
    int h  = r4 / WB;
    int wb = r4 - h * WB;

    const float* tb = (s4 < 2) ? (up_sal + (size_t)s4 * 8 * NPIX)
                               : (up_sal_f + (size_t)(s4 - 2) * 8 * NPIX);
    const float* base = tb + (size_t)b * 8 * IMG;  // this batch's 8 planes

    unsigned int pk = packed[g];
    f4 tgt = *(const f4*)(target + 4 * (size_t)g);

    const int drs[8] = {-1, -1, -1,  0, 0,  1, 1, 1};
    const int dcs[8] = {-1,  0,  1, -1, 1, -1, 0, 1};

    f4 xc[8], xn[8];
    float hok[8];
    #pragma unroll
    for (int k = 0; k < 8; k++) {
        xc[k] = *(const f4*)(base + (size_t)k * IMG + 4 * (size_t)r4);
        int h2 = h + drs[k];
        long off = (long)(7 - k) * IMG + (long)h2 * WW + 4 * wb + dcs[k];
        off = off < 0 ? 0 : off;
        off = off > (long)(8 * IMG - 4) ? (long)(8 * IMG - 4) : off;
        xn[k] = loadu4(base + off);
        hok[k] = ((unsigned)h2 < (unsigned)HH) ? 1.0f : 0.0f;
    }

    float local = 0.0f;
    #pragma unroll
    for (int j = 0; j < 4; j++) {
        unsigned int byte = (pk >> (8 * j)) & 0xffu;
        int s = __popc(byte);
        float em = (s > 0 && s < 8) ? 1.0f : 0.0f;

        float vsum = 0.0f, vmin = 1e30f, vb = 0.0f, pb = 0.0f;
        #pragma unroll
        for (int k = 0; k < 8; k++) {
            float okc = hok[k];
            if (dcs[k] == -1 && j == 0) okc = (wb != 0)      ? okc : 0.0f;
            if (dcs[k] ==  1 && j == 3) okc = (wb != WB - 1) ? okc : 0.0f;

            float xcv = xc[k][j];
            float xnv = xn[k][j];
            float e   = __expf(-xcv);
            float pc  = rcpf_(1.0f + e);            // sigmoid(xc)
            float sc  = __logf(1.0f + e);           // -log pc
            float en  = __expf(-xnv);
            float pn  = rcpf_(1.0f + en) * okc;
            float snv = (okc != 0.0f) ? __logf(1.0f + en) : 1e30f;

            float v = pc * pn;
            vsum += v;
            vmin = fminf(vmin, v);

            float t    = (float)((byte >> k) & 1u);
            float l1mv = __logf(1.0f - v);
            float vbk  = (t != 0.0f) ? (sc + snv) : (-l1mv);
            vb += fminf(vbk, 100.0f);
            float pbk  = (t != 0.0f) ? sc : (xcv + sc);
            pb += fminf(pbk, 100.0f);
        }
        float glo = vsum * 0.125f;
        float dec = (em != 0.0f) ? (1.0f - vmin) : glo;
        float lgd  = fmaxf(__logf(dec), -100.0f);
        float lg1d = fmaxf(__logf(1.0f - dec), -100.0f);
        local += -(tgt[j] * lgd + (1.0f - tgt[j]) * lg1d) + 0.2f * vb + 0.8f * pb;
    }

    local = wave_reduce_f(local);
    __shared__ float sm[4];
    int lane = threadIdx.x & 63, wid = threadIdx.x >> 6;
    if (lane == 0) sm[wid] = local;
    __syncthreads();
    if (threadIdx.x == 0)
        atomicAdd(acc, (double)(sm[0] + sm[1] + sm[2] + sm[3]));
}

__global__ void k_final(const double* __restrict__ acc,
                        const unsigned int* __restrict__ npos,
                        float* __restrict__ out) {
    if (threadIdx.x == 0) {
        double np_  = (double)(*npos);
        double tot  = (double)NPIX;
        double nn   = tot - np_;
        double wpos = nn / tot;
        double wneg = 1.1 * np_ / tot;
        double e  = wpos * acc[0] + wneg * acc[1];
        double sl = acc[2];
        double l  = e + sl;
        out[0] = (float)l;
        out[1] = (float)e;
        out[2] = (float)sl;
        out[3] = (float)l;
    }
}

extern "C" void kernel_launch(void* const* d_in, const int* in_sizes, int n_in,
                              void* d_out, int out_size, void* d_ws, size_t ws_size,
                              hipStream_t stream) {
    const float* up_edge  = (const float*)d_in[0];  // [3,B,1,H,W]
    const float* up_sal   = (const float*)d_in[1];  // [2,B,8,H,W]
    const float* up_sal_f = (const float*)d_in[2];  // [2,B,8,H,W]
    const float* target   = (const float*)d_in[3];  // [B,1,H,W]
    const int*   con      = (const int*)d_in[4];    // [B,8,H,W]
    float* out = (float*)d_out;

    // ws: acc[0]=S_pos, acc[1]=S_neg, acc[2]=sal_l (doubles); npos uint at +24;
    //     packed con plane (NG uints) at +64
    double*       acc    = (double*)d_ws;
    unsigned int* npos   = (unsigned int*)((char*)d_ws + 24);
    unsigned int* packed = (unsigned int*)((char*)d_ws + 64);

    hipMemsetAsync(d_ws, 0, 64, stream);
    k_edge<<<GBLK, THREADS, 0, stream>>>(up_edge, con, packed, acc, npos);
    k_sal<<<dim3(GBLK, 4), THREADS, 0, stream>>>(up_sal, up_sal_f, target, packed, acc + 2);
    k_final<<<1, 64, 0, stream>>>(acc, npos, out);
}